// Round 7
// baseline (897.344 us; speedup 1.0000x reference)
//
#include <hip/hip_runtime.h>
#include <math.h>

typedef unsigned short u16;
typedef unsigned int u32;
typedef __attribute__((ext_vector_type(4))) float f32x4;
typedef __attribute__((ext_vector_type(4))) u32 u32x4;
typedef __attribute__((ext_vector_type(8))) short s16x8;
typedef __attribute__((ext_vector_type(8))) u16 u16x8;

__device__ __forceinline__ float bf2f(u16 h) { return __uint_as_float(((u32)h) << 16); }
__device__ __forceinline__ u16 f2bf(float f) {
    u32 u = __float_as_uint(f);
    return (u16)((u + 0x7FFFu + ((u >> 16) & 1u)) >> 16);
}
__device__ __forceinline__ void unpack8(u16x8 a, float* f) {
    const u32* p = (const u32*)&a;
#pragma unroll
    for (int k = 0; k < 4; ++k) {
        u32 w = p[k];
        f[2 * k] = __uint_as_float(w << 16);
        f[2 * k + 1] = __uint_as_float(w & 0xffff0000u);
    }
}

// ---------------- workspace layout (bytes) ----------------
#define OFF_CONV1 0ull
#define OFF_CP    104857600ull
#define OFF_UHAT  0ull
#define OFF_U     188743680ull
#define OFF_WR    198180864ull
#define OFF_WB    208797696ull
#define OFF_W1T   211746816ull
#define OFF_MASK  211829760ull
#define OFF_H1    212157440ull
#define OFF_H2    213206016ull

#define GLDS16(SRC, DST) __builtin_amdgcn_global_load_lds( \
    (const __attribute__((address_space(1))) unsigned int*)(SRC), \
    (__attribute__((address_space(3))) unsigned int*)(DST), 16, 0, 0)

// ---------------- weight prep ----------------
__global__ void k_w1t(const float* __restrict__ cw, float* __restrict__ w1t) {
    int k = blockIdx.x, t = threadIdx.x;
    w1t[k * 256 + t] = cw[t * 81 + k];
}

// coalesced transpose via LDS (two 21 KB passes): pw[och][ic][kk] -> wr[och][kk][ic]
__global__ __launch_bounds__(256) void k_wr(const float* __restrict__ pw,
                                            u16* __restrict__ wrq) {
    int och = blockIdx.x, t = threadIdx.x;
    __shared__ u16 ld[128 * 82];
    const float* src = pw + (size_t)och * 20736;
    u16* dst = wrq + (size_t)och * 20736;
    for (int half = 0; half < 2; ++half) {
        const float* s2 = src + half * 128 * 81;
        for (int i = t; i < 128 * 81; i += 256) {
            int ic = i / 81, kk = i - ic * 81;
            ld[ic * 82 + kk] = f2bf(s2[i]);
        }
        __syncthreads();
        int col = t & 127, kh = t >> 7;
        for (int kk = kh; kk < 81; kk += 2)
            dst[kk * 256 + half * 128 + col] = ld[col * 82 + kk];
        __syncthreads();
    }
}

__global__ void k_wb(const float* __restrict__ w, u16* __restrict__ o) {
    int i = (blockIdx.x * 256 + threadIdx.x) * 8;
    u16x8 r;
#pragma unroll
    for (int j = 0; j < 8; ++j) r[j] = f2bf(w[i + j]);
    *(u16x8*)&o[i] = r;
}

// ---------------- conv1 (fp32 vector) -> NHWC bf16 ----------------
__global__ __launch_bounds__(256) void k_conv1(const float* __restrict__ x,
                                               const float* __restrict__ w1t,
                                               const float* __restrict__ bias,
                                               u16* __restrict__ out) {
    int b = blockIdx.x / 20, y = blockIdx.x % 20, t = threadIdx.x;
    __shared__ float xs[252];
    if (t < 252) xs[t] = x[b * 784 + y * 28 + t];
    __syncthreads();
    float acc[20];
#pragma unroll
    for (int i = 0; i < 20; ++i) acc[i] = 0.f;
#pragma unroll
    for (int ky = 0; ky < 9; ++ky) {
        float xr[28];
#pragma unroll
        for (int i = 0; i < 28; ++i) xr[i] = xs[ky * 28 + i];
#pragma unroll
        for (int kx = 0; kx < 9; ++kx) {
            float wv = w1t[(ky * 9 + kx) * 256 + t];
#pragma unroll
            for (int ox = 0; ox < 20; ++ox) acc[ox] += wv * xr[ox + kx];
        }
    }
    float bv = bias[t];
    u16* op = out + ((size_t)(b * 20 + y) * 20) * 256 + t;
#pragma unroll
    for (int ox = 0; ox < 20; ++ox) {
        float f = fmaxf(acc[ox] + bv, 0.f);
        op[ox * 256] = f2bf(f);
    }
}

// ---------------- primary caps: implicit GEMM, MFMA bf16, split-K=2 ----------------
// single-buffered (32KB LDS, high occupancy — dbuf regressed, see R6 post-mortem)
__global__ __launch_bounds__(256) void k_gemm(const u16* __restrict__ wr,
                                              const u16* __restrict__ cin,
                                              float* __restrict__ cp) {
    __shared__ __align__(16) u16 Al[128 * 64];
    __shared__ __align__(16) u16 Bl[128 * 64];
    int tid = threadIdx.x, lane = tid & 63, w = tid >> 6;
    int pix0 = blockIdx.x * 128, och0 = blockIdx.y * 128, q = blockIdx.z;
    int kbase = q * 10368;
    int slot = lane & 7;
    const char* ab[4];
    const char* bb[4];
#pragma unroll
    for (int j = 0; j < 4; ++j) {
        int r = w * 32 + j * 8 + (lane >> 3);
        int sl = slot ^ (r & 7);
        ab[j] = (const char*)wr + (size_t)(och0 + r) * 41472 + sl * 16;
        int p = pix0 + r, bi = p / 36, rr = p % 36, yy = rr / 6, xx = rr % 6;
        bb[j] = (const char*)cin + (size_t)((bi * 20 + 2 * yy) * 20 + 2 * xx) * 512 + sl * 16;
    }
    f32x4 acc[4][4];
#pragma unroll
    for (int i = 0; i < 4; ++i)
#pragma unroll
        for (int j = 0; j < 4; ++j) acc[i][j] = (f32x4){0.f, 0.f, 0.f, 0.f};
    int wm = (w & 1) * 64, wn = (w >> 1) * 64;

    for (int it = 0; it < 162; ++it) {
        int kk0 = kbase + it * 64;
        int kykx = kk0 >> 8, ic0 = kk0 & 255;
        int aoffu = kk0 * 2;
        int boffu = ((kykx / 9) * 20 + (kykx % 9)) * 512 + ic0 * 2;
#pragma unroll
        for (int j = 0; j < 4; ++j) {
            GLDS16(ab[j] + aoffu, &Al[(w * 32 + j * 8) * 64]);
            GLDS16(bb[j] + boffu, &Bl[(w * 32 + j * 8) * 64]);
        }
        __syncthreads();
#pragma unroll
        for (int s = 0; s < 2; ++s) {
            s16x8 af[4], bf[4];
#pragma unroll
            for (int f = 0; f < 4; ++f) {
                int m = wm + f * 16 + (lane & 15);
                int ch = ((s << 2) + (lane >> 4)) ^ (m & 7);
                af[f] = *(const s16x8*)&Al[m * 64 + ch * 8];
                int n = wn + f * 16 + (lane & 15);
                int ch2 = ((s << 2) + (lane >> 4)) ^ (n & 7);
                bf[f] = *(const s16x8*)&Bl[n * 64 + ch2 * 8];
            }
#pragma unroll
            for (int fm = 0; fm < 4; ++fm)
#pragma unroll
                for (int fn = 0; fn < 4; ++fn)
                    acc[fm][fn] = __builtin_amdgcn_mfma_f32_16x16x32_bf16(
                        af[fm], bf[fn], acc[fm][fn], 0, 0, 0);
        }
        __syncthreads();
    }
#pragma unroll
    for (int fm = 0; fm < 4; ++fm) {
        int och = och0 + wm + fm * 16 + (lane >> 4) * 4;
#pragma unroll
        for (int fn = 0; fn < 4; ++fn) {
            int pix = pix0 + wn + fn * 16 + (lane & 15);
            *(f32x4*)&cp[(((size_t)q * 18432 + pix) << 8) + och] = acc[fm][fn];
        }
    }
}

// ---------------- reduce split-K partials + bias + squash -> u bf16 ----------------
__global__ void k_squash(const float* __restrict__ cp, const float* __restrict__ pbias,
                         u16* __restrict__ u) {
    int idx = blockIdx.x * 256 + threadIdx.x;
    int pix = idx >> 5, g = idx & 31;
    size_t base = ((size_t)pix << 8) + g * 8;
    f32x4 s0 = {0.f, 0.f, 0.f, 0.f}, s1 = {0.f, 0.f, 0.f, 0.f};
#pragma unroll
    for (int q = 0; q < 2; ++q) {
        s0 += *(const f32x4*)&cp[q * 4718592ull + base];
        s1 += *(const f32x4*)&cp[q * 4718592ull + base + 4];
    }
    s0 += *(const f32x4*)&pbias[g * 8];
    s1 += *(const f32x4*)&pbias[g * 8 + 4];
    float sq = s0.x * s0.x + s0.y * s0.y + s0.z * s0.z + s0.w * s0.w +
               s1.x * s1.x + s1.y * s1.y + s1.z * s1.z + s1.w * s1.w;
    float scale = (sq / (1.f + sq)) / (sqrtf(sq) + 1e-8f);
    int b = pix / 36, cap = g * 36 + pix % 36;
    u16x8 r;
    r[0] = f2bf(s0.x * scale); r[1] = f2bf(s0.y * scale);
    r[2] = f2bf(s0.z * scale); r[3] = f2bf(s0.w * scale);
    r[4] = f2bf(s1.x * scale); r[5] = f2bf(s1.y * scale);
    r[6] = f2bf(s1.z * scale); r[7] = f2bf(s1.w * scale);
    *(u16x8*)&u[((size_t)b * 1152 + cap) * 8] = r;
}

// ---------------- u_hat -> pair layout [b][c2][o][d][2] (u32 = 2xbf16) ----------------
__global__ __launch_bounds__(256) void k_uhat(const u16* __restrict__ u,
                                              const u16* __restrict__ wb,
                                              u32* __restrict__ uhp) {
    int o = blockIdx.x, cg = blockIdx.y, bq = blockIdx.z, t = threadIdx.x;
    __shared__ __align__(16) u16 wl[64 * 136];   // pad 128->136 u16 per c
    const u16* wsrc = wb + ((size_t)o * 1152 + cg * 64) * 128;
    for (int i = t; i < 1024; i += 256) {
        int row = i >> 4, j = i & 15;
        *(u16x8*)&wl[row * 136 + j * 8] = *(const u16x8*)&wsrc[i * 8];
    }
    __syncthreads();
    int bl = t >> 5, c2l = t & 31;
    const u16* w0p = &wl[(2 * c2l) * 136];
    const u16* w1p = &wl[(2 * c2l + 1) * 136];
    for (int bt = bq * 16; bt < bq * 16 + 16; ++bt) {
        int b = bt * 8 + bl;
        const u16x8* up = (const u16x8*)(u + ((size_t)b * 1152 + cg * 64 + 2 * c2l) * 8);
        float u0[8], u1[8];
        unpack8(up[0], u0);
        unpack8(up[1], u1);
        u32 outv[16];
#pragma unroll
        for (int d = 0; d < 16; ++d) {
            u16x8 wv0 = *(const u16x8*)&w0p[d * 8];
            u16x8 wv1 = *(const u16x8*)&w1p[d * 8];
            float w0f[8], w1f[8];
            unpack8(wv0, w0f);
            unpack8(wv1, w1f);
            float dA = 0.f, dB = 0.f;
#pragma unroll
            for (int i = 0; i < 8; ++i) {
                dA += w0f[i] * u0[i];
                dB += w1f[i] * u1[i];
            }
            outv[d] = (u32)f2bf(dA) | ((u32)f2bf(dB) << 16);
        }
        u32* dst = uhp + (size_t)b * 92160 + (cg * 32 + c2l) * 160 + o * 16;
#pragma unroll
        for (int k = 0; k < 4; ++k)
            *(u32x4*)&dst[k * 4] = *(u32x4*)&outv[k * 4];
    }
}

// ---------------- fused dynamic routing: 3 streaming passes ----------------
__global__ __launch_bounds__(256, 2) void k_routing(const u32* __restrict__ uhp,
                                                    float* __restrict__ logits,
                                                    float* __restrict__ masked) {
    int b = blockIdx.x, t = threadIdx.x;
    __shared__ float blog[10][1160];          // 46.4 KB
    __shared__ __align__(16) u32 chunk[32 * 164];  // 21 KB, row stride 164 u32
    __shared__ float cwl[10][66];
    __shared__ float v[160];
    __shared__ float lg[10];
    __shared__ int am;
    for (int i = t; i < 11600; i += 256) ((float*)blog)[i] = 0.f;
    const u32* uh = uhp + (size_t)b * 92160;
    int o16 = t >> 4, d16 = t & 15;
    float s = 0.f;
    __syncthreads();

    // ---- pass 0: uniform coupling 1/10 ----
    if (t < 160) {
        const u32* p = uh + t;
#pragma unroll 8
        for (int c2 = 0; c2 < 576; ++c2) {
            u32 wv = p[c2 * 160];
            s += bf2f((u16)(wv & 0xffffu)) + bf2f((u16)(wv >> 16));
        }
        s *= 0.1f;
        float sq = s * s;
        sq += __shfl_xor(sq, 1, 16);
        sq += __shfl_xor(sq, 2, 16);
        sq += __shfl_xor(sq, 4, 16);
        sq += __shfl_xor(sq, 8, 16);
        float scale = (sq / (1.f + sq)) / (sqrtf(sq) + 1e-8f);
        v[t] = s * scale;
    }
    __syncthreads();

    for (int pass = 1; pass < 3; ++pass) {
        float snew = 0.f;
        for (int cg = 0; cg < 18; ++cg) {
            const u32x4* src4 = (const u32x4*)(uh + (size_t)cg * 5120);
#pragma unroll
            for (int k = 0; k < 5; ++k) {
                int idx4 = t + k * 256;
                int c2l = idx4 / 40, j4 = idx4 - c2l * 40;
                ((u32x4*)chunk)[c2l * 41 + j4] = src4[idx4];
            }
            __syncthreads();
#pragma unroll
            for (int jj = 0; jj < 2; ++jj) {
                int idx = t + jj * 256;
                if (idx < 320) {
                    int c2l = idx / 10, o = idx - c2l * 10;
                    const u32* row = &chunk[c2l * 164 + o * 16];
                    const float* vp = &v[o * 16];
                    float d0 = 0.f, d1 = 0.f;
#pragma unroll
                    for (int d = 0; d < 16; ++d) {
                        u32 wv = row[d];
                        float vv = vp[d];
                        d0 += __uint_as_float(wv << 16) * vv;
                        d1 += __uint_as_float(wv & 0xffff0000u) * vv;
                    }
                    int c2 = cg * 32 + c2l;
                    blog[o][2 * c2] += d0;
                    blog[o][2 * c2 + 1] += d1;
                }
            }
            __syncthreads();
            if (t < 64) {
                int c = cg * 64 + t;
                float bb[10], mx = -1e30f;
#pragma unroll
                for (int o = 0; o < 10; ++o) { bb[o] = blog[o][c]; mx = fmaxf(mx, bb[o]); }
                float sum = 0.f;
#pragma unroll
                for (int o = 0; o < 10; ++o) { bb[o] = __expf(bb[o] - mx); sum += bb[o]; }
                float rs = 1.f / sum;
#pragma unroll
                for (int o = 0; o < 10; ++o) cwl[o][t] = bb[o] * rs;
            }
            __syncthreads();
            if (t < 160) {
                const u32* col = &chunk[t];
                const float* cwp = &cwl[o16][0];
#pragma unroll 8
                for (int c2l = 0; c2l < 32; ++c2l) {
                    u32 wv = col[c2l * 164];
                    snew += __uint_as_float(wv << 16) * cwp[2 * c2l] +
                            __uint_as_float(wv & 0xffff0000u) * cwp[2 * c2l + 1];
                }
            }
            __syncthreads();
        }
        if (t < 160) {
            s = snew;
            float sq = s * s;
            sq += __shfl_xor(sq, 1, 16);
            sq += __shfl_xor(sq, 2, 16);
            sq += __shfl_xor(sq, 4, 16);
            sq += __shfl_xor(sq, 8, 16);
            float scale = (sq / (1.f + sq)) / (sqrtf(sq) + 1e-8f);
            v[t] = s * scale;
            if (d16 == 0 && pass == 2) {
                float sn = sqrtf(sq);
                float l = (sq / (1.f + sq)) * (sn / (sn + 1e-8f));
                lg[o16] = l;
                logits[b * 10 + o16] = l;
            }
        }
        __syncthreads();
    }
    if (t == 0) {
        float best = lg[0];
        int bi = 0;
#pragma unroll
        for (int o = 1; o < 10; ++o)
            if (lg[o] > best) { best = lg[o]; bi = o; }
        am = bi;
    }
    __syncthreads();
    if (t < 160) masked[b * 160 + t] = (o16 == am) ? v[t] : 0.f;
}

// ---------------- decoder layer (8-batch tile) ----------------
template <int K, int OUTDIM, int ACT>
__global__ __launch_bounds__(256) void k_dec(const float* __restrict__ in,
                                             const float* __restrict__ W,
                                             const float* __restrict__ bias,
                                             float* __restrict__ out) {
    int bt = blockIdx.y * 8;
    int o = blockIdx.x * 256 + threadIdx.x;
    __shared__ float ins[8 * K];
    for (int i = threadIdx.x; i < 8 * K; i += 256) ins[i] = in[(size_t)bt * K + i];
    __syncthreads();
    if (o < OUTDIM) {
        float acc[8];
#pragma unroll
        for (int bb = 0; bb < 8; ++bb) acc[bb] = 0.f;
        const float* wr = W + (size_t)o * K;
#pragma unroll 4
        for (int k = 0; k < K; ++k) {
            float wv = wr[k];
#pragma unroll
            for (int bb = 0; bb < 8; ++bb) acc[bb] += wv * ins[bb * K + k];
        }
        float bv = bias[o];
#pragma unroll
        for (int bb = 0; bb < 8; ++bb) {
            float z = acc[bb] + bv;
            float r = (ACT == 0) ? fmaxf(z, 0.f) : 1.f / (1.f + __expf(-z));
            out[(size_t)(bt + bb) * OUTDIM + o] = r;
        }
    }
}

extern "C" void kernel_launch(void* const* d_in, const int* in_sizes, int n_in,
                              void* d_out, int out_size, void* d_ws, size_t ws_size,
                              hipStream_t stream) {
    const float* x       = (const float*)d_in[0];
    const float* conv1_w = (const float*)d_in[1];
    const float* conv1_b = (const float*)d_in[2];
    const float* prim_w  = (const float*)d_in[3];
    const float* prim_b  = (const float*)d_in[4];
    const float* W_digit = (const float*)d_in[5];
    const float* dec_w1  = (const float*)d_in[6];
    const float* dec_b1  = (const float*)d_in[7];
    const float* dec_w2  = (const float*)d_in[8];
    const float* dec_b2  = (const float*)d_in[9];
    const float* dec_w3  = (const float*)d_in[10];
    const float* dec_b3  = (const float*)d_in[11];

    char* ws = (char*)d_ws;
    u16*   conv1o = (u16*)(ws + OFF_CONV1);
    float* cp     = (float*)(ws + OFF_CP);
    u32*   uhat   = (u32*)(ws + OFF_UHAT);
    u16*   u      = (u16*)(ws + OFF_U);
    u16*   wrq    = (u16*)(ws + OFF_WR);
    u16*   wb     = (u16*)(ws + OFF_WB);
    float* w1t    = (float*)(ws + OFF_W1T);
    float* maskd  = (float*)(ws + OFF_MASK);
    float* h1     = (float*)(ws + OFF_H1);
    float* h2     = (float*)(ws + OFF_H2);
    float* logits = (float*)d_out;
    float* recon  = (float*)d_out + 5120;

    k_w1t<<<dim3(81), dim3(256), 0, stream>>>(conv1_w, w1t);
    k_wr<<<dim3(256), dim3(256), 0, stream>>>(prim_w, wrq);
    k_wb<<<dim3(720), dim3(256), 0, stream>>>(W_digit, wb);
    k_conv1<<<dim3(10240), dim3(256), 0, stream>>>(x, w1t, conv1_b, conv1o);
    k_gemm<<<dim3(144, 2, 2), dim3(256), 0, stream>>>(wrq, conv1o, cp);
    k_squash<<<dim3(2304), dim3(256), 0, stream>>>(cp, prim_b, u);
    k_uhat<<<dim3(10, 18, 4), dim3(256), 0, stream>>>(u, wb, uhat);
    k_routing<<<dim3(512), dim3(256), 0, stream>>>(uhat, logits, maskd);
    k_dec<160, 512, 0><<<dim3(2, 64), dim3(256), 0, stream>>>(maskd, dec_w1, dec_b1, h1);
    k_dec<512, 1024, 0><<<dim3(4, 64), dim3(256), 0, stream>>>(h1, dec_w2, dec_b2, h2);
    k_dec<1024, 784, 1><<<dim3(4, 64), dim3(256), 0, stream>>>(h2, dec_w3, dec_b3, recon);
}

// Round 8
// 723.770 us; speedup vs baseline: 1.2398x; 1.2398x over previous
//
#include <hip/hip_runtime.h>
#include <math.h>

typedef unsigned short u16;
typedef unsigned int u32;
typedef __attribute__((ext_vector_type(4))) float f32x4;
typedef __attribute__((ext_vector_type(4))) u32 u32x4;
typedef __attribute__((ext_vector_type(8))) short s16x8;
typedef __attribute__((ext_vector_type(8))) u16 u16x8;
typedef __attribute__((ext_vector_type(4))) u16 u16x4;

__device__ __forceinline__ float bf2f(u16 h) { return __uint_as_float(((u32)h) << 16); }
__device__ __forceinline__ u16 f2bf(float f) {
    u32 u = __float_as_uint(f);
    return (u16)((u + 0x7FFFu + ((u >> 16) & 1u)) >> 16);
}
__device__ __forceinline__ void unpack8(u16x8 a, float* f) {
    const u32* p = (const u32*)&a;
#pragma unroll
    for (int k = 0; k < 4; ++k) {
        u32 w = p[k];
        f[2 * k] = __uint_as_float(w << 16);
        f[2 * k + 1] = __uint_as_float(w & 0xffff0000u);
    }
}

// ---------------- workspace layout (bytes) ----------------
#define OFF_CONV1 0ull
#define OFF_CP    104857600ull
#define OFF_UHAT  0ull
#define OFF_U     188743680ull
#define OFF_WR    198180864ull
#define OFF_WB    208797696ull
#define OFF_W1T   211746816ull
#define OFF_MASK  211829760ull
#define OFF_H1    212157440ull
#define OFF_H2    213206016ull

#define GLDS16(SRC, DST) __builtin_amdgcn_global_load_lds( \
    (const __attribute__((address_space(1))) unsigned int*)(SRC), \
    (__attribute__((address_space(3))) unsigned int*)(DST), 16, 0, 0)

// ---------------- merged weight prep ----------------
// blocks [0,81): conv1 w transpose ; [81,801): W_digit->bf16 ; [801,1057): prim_w transpose
__global__ __launch_bounds__(256) void k_prep(const float* __restrict__ cw,
                                              float* __restrict__ w1t,
                                              const float* __restrict__ wdig,
                                              u16* __restrict__ wb,
                                              const float* __restrict__ pw,
                                              u16* __restrict__ wrq) {
    __shared__ u16 ld[128 * 82];
    int bid = blockIdx.x, t = threadIdx.x;
    if (bid < 81) {
        w1t[bid * 256 + t] = cw[t * 81 + bid];
    } else if (bid < 801) {
        int i = ((bid - 81) * 256 + t) * 8;
        u16x8 r;
#pragma unroll
        for (int j = 0; j < 8; ++j) r[j] = f2bf(wdig[i + j]);
        *(u16x8*)&wb[i] = r;
    } else {
        int och = bid - 801;
        const float* src = pw + (size_t)och * 20736;
        u16* dst = wrq + (size_t)och * 20736;
        for (int half = 0; half < 2; ++half) {
            const float* s2 = src + half * 128 * 81;
            for (int i = t; i < 128 * 81; i += 256) {
                int ic = i / 81, kk = i - ic * 81;
                ld[ic * 82 + kk] = f2bf(s2[i]);
            }
            __syncthreads();
            int col = t & 127, kh = t >> 7;
            for (int kk = kh; kk < 81; kk += 2)
                dst[kk * 256 + half * 128 + col] = ld[col * 82 + kk];
            __syncthreads();
        }
    }
}

// ---------------- conv1 (fp32 vector) -> NHWC bf16 ----------------
__global__ __launch_bounds__(256) void k_conv1(const float* __restrict__ x,
                                               const float* __restrict__ w1t,
                                               const float* __restrict__ bias,
                                               u16* __restrict__ out) {
    int b = blockIdx.x / 20, y = blockIdx.x % 20, t = threadIdx.x;
    __shared__ float xs[252];
    if (t < 252) xs[t] = x[b * 784 + y * 28 + t];
    __syncthreads();
    float acc[20];
#pragma unroll
    for (int i = 0; i < 20; ++i) acc[i] = 0.f;
#pragma unroll
    for (int ky = 0; ky < 9; ++ky) {
        float xr[28];
#pragma unroll
        for (int i = 0; i < 28; ++i) xr[i] = xs[ky * 28 + i];
#pragma unroll
        for (int kx = 0; kx < 9; ++kx) {
            float wv = w1t[(ky * 9 + kx) * 256 + t];
#pragma unroll
            for (int ox = 0; ox < 20; ++ox) acc[ox] += wv * xr[ox + kx];
        }
    }
    float bv = bias[t];
    u16* op = out + ((size_t)(b * 20 + y) * 20) * 256 + t;
#pragma unroll
    for (int ox = 0; ox < 20; ++ox) {
        float f = fmaxf(acc[ox] + bv, 0.f);
        op[ox * 256] = f2bf(f);
    }
}

// ---------------- primary caps: implicit GEMM, MFMA bf16, split-K=4 ----------------
// R3 structure (single-buffer, 2-barrier, 1152 blocks) — bf16 partial output
__global__ __launch_bounds__(256) void k_gemm(const u16* __restrict__ wr,
                                              const u16* __restrict__ cin,
                                              u16* __restrict__ cp16) {
    __shared__ __align__(16) u16 Al[128 * 64];
    __shared__ __align__(16) u16 Bl[128 * 64];
    int tid = threadIdx.x, lane = tid & 63, w = tid >> 6;
    int pix0 = blockIdx.x * 128, och0 = blockIdx.y * 128, q = blockIdx.z;
    int kbase = q * 5184;
    int slot = lane & 7;
    const char* ab[4];
    const char* bb[4];
#pragma unroll
    for (int j = 0; j < 4; ++j) {
        int r = w * 32 + j * 8 + (lane >> 3);
        int sl = slot ^ (r & 7);
        ab[j] = (const char*)wr + (size_t)(och0 + r) * 41472 + sl * 16;
        int p = pix0 + r, bi = p / 36, rr = p % 36, yy = rr / 6, xx = rr % 6;
        bb[j] = (const char*)cin + (size_t)((bi * 20 + 2 * yy) * 20 + 2 * xx) * 512 + sl * 16;
    }
    f32x4 acc[4][4];
#pragma unroll
    for (int i = 0; i < 4; ++i)
#pragma unroll
        for (int j = 0; j < 4; ++j) acc[i][j] = (f32x4){0.f, 0.f, 0.f, 0.f};
    int wm = (w & 1) * 64, wn = (w >> 1) * 64;

    for (int it = 0; it < 81; ++it) {
        int kk0 = kbase + it * 64;
        int kykx = kk0 >> 8, ic0 = kk0 & 255;
        int aoffu = kk0 * 2;
        int boffu = ((kykx / 9) * 20 + (kykx % 9)) * 512 + ic0 * 2;
#pragma unroll
        for (int j = 0; j < 4; ++j) {
            GLDS16(ab[j] + aoffu, &Al[(w * 32 + j * 8) * 64]);
            GLDS16(bb[j] + boffu, &Bl[(w * 32 + j * 8) * 64]);
        }
        __syncthreads();
#pragma unroll
        for (int s = 0; s < 2; ++s) {
            s16x8 af[4], bf[4];
#pragma unroll
            for (int f = 0; f < 4; ++f) {
                int m = wm + f * 16 + (lane & 15);
                int ch = ((s << 2) + (lane >> 4)) ^ (m & 7);
                af[f] = *(const s16x8*)&Al[m * 64 + ch * 8];
                int n = wn + f * 16 + (lane & 15);
                int ch2 = ((s << 2) + (lane >> 4)) ^ (n & 7);
                bf[f] = *(const s16x8*)&Bl[n * 64 + ch2 * 8];
            }
#pragma unroll
            for (int fm = 0; fm < 4; ++fm)
#pragma unroll
                for (int fn = 0; fn < 4; ++fn)
                    acc[fm][fn] = __builtin_amdgcn_mfma_f32_16x16x32_bf16(
                        af[fm], bf[fn], acc[fm][fn], 0, 0, 0);
        }
        __syncthreads();
    }
#pragma unroll
    for (int fm = 0; fm < 4; ++fm) {
        int och = och0 + wm + fm * 16 + (lane >> 4) * 4;
#pragma unroll
        for (int fn = 0; fn < 4; ++fn) {
            int pix = pix0 + wn + fn * 16 + (lane & 15);
            u16x4 r;
#pragma unroll
            for (int i = 0; i < 4; ++i) r[i] = f2bf(acc[fm][fn][i]);
            *(u16x4*)&cp16[(((size_t)q * 18432 + pix) << 8) + och] = r;
        }
    }
}

// ---------------- reduce split-K bf16 partials + bias + squash -> u bf16 ----------------
__global__ void k_squash(const u16* __restrict__ cp16, const float* __restrict__ pbias,
                         u16* __restrict__ u) {
    int idx = blockIdx.x * 256 + threadIdx.x;
    int pix = idx >> 5, g = idx & 31;
    size_t base = ((size_t)pix << 8) + g * 8;
    float s[8];
#pragma unroll
    for (int i = 0; i < 8; ++i) s[i] = pbias[g * 8 + i];
#pragma unroll
    for (int q = 0; q < 4; ++q) {
        u16x8 a = *(const u16x8*)&cp16[q * 4718592ull + base];
        float f[8];
        unpack8(a, f);
#pragma unroll
        for (int i = 0; i < 8; ++i) s[i] += f[i];
    }
    float sq = 0.f;
#pragma unroll
    for (int i = 0; i < 8; ++i) sq += s[i] * s[i];
    float scale = (sq / (1.f + sq)) / (sqrtf(sq) + 1e-8f);
    int b = pix / 36, cap = g * 36 + pix % 36;
    u16x8 r;
#pragma unroll
    for (int i = 0; i < 8; ++i) r[i] = f2bf(s[i] * scale);
    *(u16x8*)&u[((size_t)b * 1152 + cap) * 8] = r;
}

// ---------------- u_hat -> pair layout [b][c2][o][d][2] (u32 = 2xbf16) ----------------
__global__ __launch_bounds__(256) void k_uhat(const u16* __restrict__ u,
                                              const u16* __restrict__ wb,
                                              u32* __restrict__ uhp) {
    int o = blockIdx.x, cg = blockIdx.y, bq = blockIdx.z, t = threadIdx.x;
    __shared__ __align__(16) u16 wl[64 * 136];   // pad 128->136 u16 per c
    const u16* wsrc = wb + ((size_t)o * 1152 + cg * 64) * 128;
    for (int i = t; i < 1024; i += 256) {
        int row = i >> 4, j = i & 15;
        *(u16x8*)&wl[row * 136 + j * 8] = *(const u16x8*)&wsrc[i * 8];
    }
    __syncthreads();
    int bl = t >> 5, c2l = t & 31;
    const u16* w0p = &wl[(2 * c2l) * 136];
    const u16* w1p = &wl[(2 * c2l + 1) * 136];
    for (int bt = bq * 16; bt < bq * 16 + 16; ++bt) {
        int b = bt * 8 + bl;
        const u16x8* up = (const u16x8*)(u + ((size_t)b * 1152 + cg * 64 + 2 * c2l) * 8);
        float u0[8], u1[8];
        unpack8(up[0], u0);
        unpack8(up[1], u1);
        u32 outv[16];
#pragma unroll
        for (int d = 0; d < 16; ++d) {
            u16x8 wv0 = *(const u16x8*)&w0p[d * 8];
            u16x8 wv1 = *(const u16x8*)&w1p[d * 8];
            float w0f[8], w1f[8];
            unpack8(wv0, w0f);
            unpack8(wv1, w1f);
            float dA = 0.f, dB = 0.f;
#pragma unroll
            for (int i = 0; i < 8; ++i) {
                dA += w0f[i] * u0[i];
                dB += w1f[i] * u1[i];
            }
            outv[d] = (u32)f2bf(dA) | ((u32)f2bf(dB) << 16);
        }
        u32* dst = uhp + (size_t)b * 92160 + (cg * 32 + c2l) * 160 + o * 16;
#pragma unroll
        for (int k = 0; k < 4; ++k)
            *(u32x4*)&dst[k * 4] = *(u32x4*)&outv[k * 4];
    }
}

// ---------------- fused dynamic routing: 3 streaming passes ----------------
__global__ __launch_bounds__(256, 2) void k_routing(const u32* __restrict__ uhp,
                                                    float* __restrict__ logits,
                                                    float* __restrict__ masked) {
    int b = blockIdx.x, t = threadIdx.x;
    __shared__ float blog[10][1160];          // 46.4 KB
    __shared__ __align__(16) u32 chunk[32 * 164];  // 21 KB, row stride 164 u32
    __shared__ float cwl[10][66];
    __shared__ float v[160];
    __shared__ float lg[10];
    __shared__ int am;
    for (int i = t; i < 11600; i += 256) ((float*)blog)[i] = 0.f;
    const u32* uh = uhp + (size_t)b * 92160;
    int o16 = t >> 4, d16 = t & 15;
    float s = 0.f;
    __syncthreads();

    // ---- pass 0: uniform coupling 1/10 ----
    if (t < 160) {
        const u32* p = uh + t;
#pragma unroll 8
        for (int c2 = 0; c2 < 576; ++c2) {
            u32 wv = p[c2 * 160];
            s += bf2f((u16)(wv & 0xffffu)) + bf2f((u16)(wv >> 16));
        }
        s *= 0.1f;
        float sq = s * s;
        sq += __shfl_xor(sq, 1, 16);
        sq += __shfl_xor(sq, 2, 16);
        sq += __shfl_xor(sq, 4, 16);
        sq += __shfl_xor(sq, 8, 16);
        float scale = (sq / (1.f + sq)) / (sqrtf(sq) + 1e-8f);
        v[t] = s * scale;
    }
    __syncthreads();

    for (int pass = 1; pass < 3; ++pass) {
        float snew = 0.f;
        for (int cg = 0; cg < 18; ++cg) {
            const u32x4* src4 = (const u32x4*)(uh + (size_t)cg * 5120);
#pragma unroll
            for (int k = 0; k < 5; ++k) {
                int idx4 = t + k * 256;
                int c2l = idx4 / 40, j4 = idx4 - c2l * 40;
                ((u32x4*)chunk)[c2l * 41 + j4] = src4[idx4];
            }
            __syncthreads();
#pragma unroll
            for (int jj = 0; jj < 2; ++jj) {
                int idx = t + jj * 256;
                if (idx < 320) {
                    int c2l = idx / 10, o = idx - c2l * 10;
                    const u32* row = &chunk[c2l * 164 + o * 16];
                    const float* vp = &v[o * 16];
                    float d0 = 0.f, d1 = 0.f;
#pragma unroll
                    for (int d = 0; d < 16; ++d) {
                        u32 wv = row[d];
                        float vv = vp[d];
                        d0 += __uint_as_float(wv << 16) * vv;
                        d1 += __uint_as_float(wv & 0xffff0000u) * vv;
                    }
                    int c2 = cg * 32 + c2l;
                    blog[o][2 * c2] += d0;
                    blog[o][2 * c2 + 1] += d1;
                }
            }
            __syncthreads();
            if (t < 64) {
                int c = cg * 64 + t;
                float bb[10], mx = -1e30f;
#pragma unroll
                for (int o = 0; o < 10; ++o) { bb[o] = blog[o][c]; mx = fmaxf(mx, bb[o]); }
                float sum = 0.f;
#pragma unroll
                for (int o = 0; o < 10; ++o) { bb[o] = __expf(bb[o] - mx); sum += bb[o]; }
                float rs = 1.f / sum;
#pragma unroll
                for (int o = 0; o < 10; ++o) cwl[o][t] = bb[o] * rs;
            }
            __syncthreads();
            if (t < 160) {
                const u32* col = &chunk[t];
                const float* cwp = &cwl[o16][0];
#pragma unroll 8
                for (int c2l = 0; c2l < 32; ++c2l) {
                    u32 wv = col[c2l * 164];
                    snew += __uint_as_float(wv << 16) * cwp[2 * c2l] +
                            __uint_as_float(wv & 0xffff0000u) * cwp[2 * c2l + 1];
                }
            }
            __syncthreads();
        }
        if (t < 160) {
            s = snew;
            float sq = s * s;
            sq += __shfl_xor(sq, 1, 16);
            sq += __shfl_xor(sq, 2, 16);
            sq += __shfl_xor(sq, 4, 16);
            sq += __shfl_xor(sq, 8, 16);
            float scale = (sq / (1.f + sq)) / (sqrtf(sq) + 1e-8f);
            v[t] = s * scale;
            if (d16 == 0 && pass == 2) {
                float sn = sqrtf(sq);
                float l = (sq / (1.f + sq)) * (sn / (sn + 1e-8f));
                lg[o16] = l;
                logits[b * 10 + o16] = l;
            }
        }
        __syncthreads();
    }
    if (t == 0) {
        float best = lg[0];
        int bi = 0;
#pragma unroll
        for (int o = 1; o < 10; ++o)
            if (lg[o] > best) { best = lg[o]; bi = o; }
        am = bi;
    }
    __syncthreads();
    if (t < 160) masked[b * 160 + t] = (o16 == am) ? v[t] : 0.f;
}

// ---------------- decoder layer (TB-batch tile) ----------------
template <int TB, int K, int OUTDIM, int ACT>
__global__ __launch_bounds__(256) void k_dec(const float* __restrict__ in,
                                             const float* __restrict__ W,
                                             const float* __restrict__ bias,
                                             float* __restrict__ out) {
    int bt = blockIdx.y * TB;
    int o = blockIdx.x * 256 + threadIdx.x;
    __shared__ float ins[TB * K];
    for (int i = threadIdx.x; i < TB * K; i += 256) ins[i] = in[(size_t)bt * K + i];
    __syncthreads();
    if (o < OUTDIM) {
        float acc[TB];
#pragma unroll
        for (int bb = 0; bb < TB; ++bb) acc[bb] = 0.f;
        const float* wr = W + (size_t)o * K;
#pragma unroll 4
        for (int k = 0; k < K; ++k) {
            float wv = wr[k];
#pragma unroll
            for (int bb = 0; bb < TB; ++bb) acc[bb] += wv * ins[bb * K + k];
        }
        float bv = bias[o];
#pragma unroll
        for (int bb = 0; bb < TB; ++bb) {
            float z = acc[bb] + bv;
            float r = (ACT == 0) ? fmaxf(z, 0.f) : 1.f / (1.f + __expf(-z));
            out[(size_t)(bt + bb) * OUTDIM + o] = r;
        }
    }
}

extern "C" void kernel_launch(void* const* d_in, const int* in_sizes, int n_in,
                              void* d_out, int out_size, void* d_ws, size_t ws_size,
                              hipStream_t stream) {
    const float* x       = (const float*)d_in[0];
    const float* conv1_w = (const float*)d_in[1];
    const float* conv1_b = (const float*)d_in[2];
    const float* prim_w  = (const float*)d_in[3];
    const float* prim_b  = (const float*)d_in[4];
    const float* W_digit = (const float*)d_in[5];
    const float* dec_w1  = (const float*)d_in[6];
    const float* dec_b1  = (const float*)d_in[7];
    const float* dec_w2  = (const float*)d_in[8];
    const float* dec_b2  = (const float*)d_in[9];
    const float* dec_w3  = (const float*)d_in[10];
    const float* dec_b3  = (const float*)d_in[11];

    char* ws = (char*)d_ws;
    u16*   conv1o = (u16*)(ws + OFF_CONV1);
    u16*   cp16   = (u16*)(ws + OFF_CP);
    u32*   uhat   = (u32*)(ws + OFF_UHAT);
    u16*   u      = (u16*)(ws + OFF_U);
    u16*   wrq    = (u16*)(ws + OFF_WR);
    u16*   wb     = (u16*)(ws + OFF_WB);
    float* w1t    = (float*)(ws + OFF_W1T);
    float* maskd  = (float*)(ws + OFF_MASK);
    float* h1     = (float*)(ws + OFF_H1);
    float* h2     = (float*)(ws + OFF_H2);
    float* logits = (float*)d_out;
    float* recon  = (float*)d_out + 5120;

    k_prep<<<dim3(1057), dim3(256), 0, stream>>>(conv1_w, w1t, W_digit, wb, prim_w, wrq);
    k_conv1<<<dim3(10240), dim3(256), 0, stream>>>(x, w1t, conv1_b, conv1o);
    k_gemm<<<dim3(144, 2, 4), dim3(256), 0, stream>>>(wrq, conv1o, cp16);
    k_squash<<<dim3(2304), dim3(256), 0, stream>>>(cp16, prim_b, u);
    k_uhat<<<dim3(10, 18, 4), dim3(256), 0, stream>>>(u, wb, uhat);
    k_routing<<<dim3(512), dim3(256), 0, stream>>>(uhat, logits, maskd);
    k_dec<4, 160, 512, 0><<<dim3(2, 128), dim3(256), 0, stream>>>(maskd, dec_w1, dec_b1, h1);
    k_dec<8, 512, 1024, 0><<<dim3(4, 64), dim3(256), 0, stream>>>(h1, dec_w2, dec_b2, h2);
    k_dec<8, 1024, 784, 1><<<dim3(4, 64), dim3(256), 0, stream>>>(h2, dec_w3, dec_b3, recon);
}

// Round 9
// 700.747 us; speedup vs baseline: 1.2806x; 1.0329x over previous
//
#include <hip/hip_runtime.h>
#include <math.h>

typedef unsigned short u16;
typedef unsigned int u32;
typedef __attribute__((ext_vector_type(4))) float f32x4;
typedef __attribute__((ext_vector_type(4))) u32 u32x4;
typedef __attribute__((ext_vector_type(8))) short s16x8;
typedef __attribute__((ext_vector_type(8))) u16 u16x8;
typedef __attribute__((ext_vector_type(4))) u16 u16x4;

__device__ __forceinline__ float bf2f(u16 h) { return __uint_as_float(((u32)h) << 16); }
__device__ __forceinline__ u16 f2bf(float f) {
    u32 u = __float_as_uint(f);
    return (u16)((u + 0x7FFFu + ((u >> 16) & 1u)) >> 16);
}
__device__ __forceinline__ void unpack8(u16x8 a, float* f) {
    const u32* p = (const u32*)&a;
#pragma unroll
    for (int k = 0; k < 4; ++k) {
        u32 w = p[k];
        f[2 * k] = __uint_as_float(w << 16);
        f[2 * k + 1] = __uint_as_float(w & 0xffff0000u);
    }
}

// ---------------- workspace layout (bytes) ----------------
#define OFF_CONV1 0ull
#define OFF_CP    104857600ull
#define OFF_UHAT  0ull
#define OFF_U     188743680ull
#define OFF_WR    198180864ull   // wrq (gemm weights); reused as s0p after gemm
#define OFF_WB    208797696ull
#define OFF_WC2   211746816ull
#define OFF_MASK  211829760ull
#define OFF_H1    212157440ull
#define OFF_H2    213206016ull

#define GLDS16(SRC, DST) __builtin_amdgcn_global_load_lds( \
    (const __attribute__((address_space(1))) unsigned int*)(SRC), \
    (__attribute__((address_space(3))) unsigned int*)(DST), 16, 0, 0)

// ---------------- merged weight prep ----------------
// [0,720): W_digit->bf16 ; [720,976): prim_w transpose ; 976: conv1 w -> wc2[256][96] padded
__global__ __launch_bounds__(256) void k_prep(const float* __restrict__ cw,
                                              u16* __restrict__ wc2,
                                              const float* __restrict__ wdig,
                                              u16* __restrict__ wb,
                                              const float* __restrict__ pw,
                                              u16* __restrict__ wrq) {
    __shared__ u16 ld[128 * 82];
    int bid = blockIdx.x, t = threadIdx.x;
    if (bid < 720) {
        int i = (bid * 256 + t) * 8;
        u16x8 r;
#pragma unroll
        for (int j = 0; j < 8; ++j) r[j] = f2bf(wdig[i + j]);
        *(u16x8*)&wb[i] = r;
    } else if (bid < 976) {
        int och = bid - 720;
        const float* src = pw + (size_t)och * 20736;
        u16* dst = wrq + (size_t)och * 20736;
        for (int half = 0; half < 2; ++half) {
            const float* s2 = src + half * 128 * 81;
            for (int i = t; i < 128 * 81; i += 256) {
                int ic = i / 81, kk = i - ic * 81;
                ld[ic * 82 + kk] = f2bf(s2[i]);
            }
            __syncthreads();
            int col = t & 127, kh = t >> 7;
            for (int kk = kh; kk < 81; kk += 2)
                dst[kk * 256 + half * 128 + col] = ld[col * 82 + kk];
            __syncthreads();
        }
    } else {
        for (int k = 0; k < 96; ++k)
            wc2[t * 96 + k] = (k < 81) ? f2bf(cw[t * 81 + k]) : (u16)0;
    }
}

// ---------------- conv1 as MFMA implicit GEMM (K=81 pad 96) -> NHWC bf16 ----------------
__global__ __launch_bounds__(256) void k_conv1(const float* __restrict__ x,
                                               const u16* __restrict__ wc2,
                                               const float* __restrict__ bias,
                                               u16* __restrict__ out) {
    int b = blockIdx.x, tid = threadIdx.x, lane = tid & 63, w = tid >> 6;
    __shared__ u16 xsb[784];
    __shared__ float bs[256];
    bs[tid] = bias[tid];
    for (int i = tid; i < 784; i += 256) xsb[i] = f2bf(x[b * 784 + i]);
    __syncthreads();
    int wm = w * 64, l15 = lane & 15, lh = lane >> 4;
    s16x8 afr[3][4];
#pragma unroll
    for (int s = 0; s < 3; ++s)
#pragma unroll
        for (int f = 0; f < 4; ++f)
            afr[s][f] = *(const s16x8*)&wc2[(wm + f * 16 + l15) * 96 + s * 32 + lh * 8];
    int off[24];
#pragma unroll
    for (int s = 0; s < 3; ++s)
#pragma unroll
        for (int j = 0; j < 8; ++j) {
            int k = s * 32 + lh * 8 + j;
            off[s * 8 + j] = (k < 81) ? ((k / 9) * 28 + (k % 9)) : 0;
        }
    for (int nt = 0; nt < 25; ++nt) {
        int p = nt * 16 + l15;
        int base = (p / 20) * 28 + (p % 20);
        s16x8 bfr[3];
#pragma unroll
        for (int s = 0; s < 3; ++s) {
#pragma unroll
            for (int j = 0; j < 8; ++j)
                bfr[s][j] = (short)xsb[base + off[s * 8 + j]];
        }
#pragma unroll
        for (int f = 0; f < 4; ++f) {
            f32x4 acc = (f32x4){0.f, 0.f, 0.f, 0.f};
#pragma unroll
            for (int s = 0; s < 3; ++s)
                acc = __builtin_amdgcn_mfma_f32_16x16x32_bf16(afr[s][f], bfr[s], acc, 0, 0, 0);
            int och = wm + f * 16 + lh * 4;
            u16x4 r;
#pragma unroll
            for (int i = 0; i < 4; ++i) r[i] = f2bf(fmaxf(acc[i] + bs[och + i], 0.f));
            *(u16x4*)&out[((size_t)b * 400 + p) * 256 + och] = r;
        }
    }
}

// ---------------- primary caps: implicit GEMM, MFMA bf16, split-K=4 ----------------
__global__ __launch_bounds__(256) void k_gemm(const u16* __restrict__ wr,
                                              const u16* __restrict__ cin,
                                              u16* __restrict__ cp16) {
    __shared__ __align__(16) u16 Al[128 * 64];
    __shared__ __align__(16) u16 Bl[128 * 64];
    int tid = threadIdx.x, lane = tid & 63, w = tid >> 6;
    int pix0 = blockIdx.x * 128, och0 = blockIdx.y * 128, q = blockIdx.z;
    int kbase = q * 5184;
    int slot = lane & 7;
    const char* ab[4];
    const char* bb[4];
#pragma unroll
    for (int j = 0; j < 4; ++j) {
        int r = w * 32 + j * 8 + (lane >> 3);
        int sl = slot ^ (r & 7);
        ab[j] = (const char*)wr + (size_t)(och0 + r) * 41472 + sl * 16;
        int p = pix0 + r, bi = p / 36, rr = p % 36, yy = rr / 6, xx = rr % 6;
        bb[j] = (const char*)cin + (size_t)((bi * 20 + 2 * yy) * 20 + 2 * xx) * 512 + sl * 16;
    }
    f32x4 acc[4][4];
#pragma unroll
    for (int i = 0; i < 4; ++i)
#pragma unroll
        for (int j = 0; j < 4; ++j) acc[i][j] = (f32x4){0.f, 0.f, 0.f, 0.f};
    int wm = (w & 1) * 64, wn = (w >> 1) * 64;

    for (int it = 0; it < 81; ++it) {
        int kk0 = kbase + it * 64;
        int kykx = kk0 >> 8, ic0 = kk0 & 255;
        int aoffu = kk0 * 2;
        int boffu = ((kykx / 9) * 20 + (kykx % 9)) * 512 + ic0 * 2;
#pragma unroll
        for (int j = 0; j < 4; ++j) {
            GLDS16(ab[j] + aoffu, &Al[(w * 32 + j * 8) * 64]);
            GLDS16(bb[j] + boffu, &Bl[(w * 32 + j * 8) * 64]);
        }
        __syncthreads();
#pragma unroll
        for (int s = 0; s < 2; ++s) {
            s16x8 af[4], bf[4];
#pragma unroll
            for (int f = 0; f < 4; ++f) {
                int m = wm + f * 16 + (lane & 15);
                int ch = ((s << 2) + (lane >> 4)) ^ (m & 7);
                af[f] = *(const s16x8*)&Al[m * 64 + ch * 8];
                int n = wn + f * 16 + (lane & 15);
                int ch2 = ((s << 2) + (lane >> 4)) ^ (n & 7);
                bf[f] = *(const s16x8*)&Bl[n * 64 + ch2 * 8];
            }
#pragma unroll
            for (int fm = 0; fm < 4; ++fm)
#pragma unroll
                for (int fn = 0; fn < 4; ++fn)
                    acc[fm][fn] = __builtin_amdgcn_mfma_f32_16x16x32_bf16(
                        af[fm], bf[fn], acc[fm][fn], 0, 0, 0);
        }
        __syncthreads();
    }
#pragma unroll
    for (int fm = 0; fm < 4; ++fm) {
        int och = och0 + wm + fm * 16 + (lane >> 4) * 4;
#pragma unroll
        for (int fn = 0; fn < 4; ++fn) {
            int pix = pix0 + wn + fn * 16 + (lane & 15);
            u16x4 r;
#pragma unroll
            for (int i = 0; i < 4; ++i) r[i] = f2bf(acc[fm][fn][i]);
            *(u16x4*)&cp16[(((size_t)q * 18432 + pix) << 8) + och] = r;
        }
    }
}

// ---------------- reduce split-K bf16 partials + bias + squash -> u bf16 ----------------
__global__ void k_squash(const u16* __restrict__ cp16, const float* __restrict__ pbias,
                         u16* __restrict__ u) {
    int idx = blockIdx.x * 256 + threadIdx.x;
    int pix = idx >> 5, g = idx & 31;
    size_t base = ((size_t)pix << 8) + g * 8;
    float s[8];
#pragma unroll
    for (int i = 0; i < 8; ++i) s[i] = pbias[g * 8 + i];
#pragma unroll
    for (int q = 0; q < 4; ++q) {
        u16x8 a = *(const u16x8*)&cp16[q * 4718592ull + base];
        float f[8];
        unpack8(a, f);
#pragma unroll
        for (int i = 0; i < 8; ++i) s[i] += f[i];
    }
    float sq = 0.f;
#pragma unroll
    for (int i = 0; i < 8; ++i) sq += s[i] * s[i];
    float scale = (sq / (1.f + sq)) / (sqrtf(sq) + 1e-8f);
    int b = pix / 36, cap = g * 36 + pix % 36;
    u16x8 r;
#pragma unroll
    for (int i = 0; i < 8; ++i) r[i] = f2bf(s[i] * scale);
    *(u16x8*)&u[((size_t)b * 1152 + cap) * 8] = r;
}

// ---------------- u_hat -> pair layout [b][c2][o][d][2] + s0p partial sums ----------------
__global__ __launch_bounds__(256) void k_uhat(const u16* __restrict__ u,
                                              const u16* __restrict__ wb,
                                              u32* __restrict__ uhp,
                                              float* __restrict__ s0p) {
    int o = blockIdx.x, cg = blockIdx.y, bq = blockIdx.z, t = threadIdx.x;
    __shared__ __align__(16) u16 wl[64 * 136];   // pad 128->136 u16 per c
    const u16* wsrc = wb + ((size_t)o * 1152 + cg * 64) * 128;
    for (int i = t; i < 1024; i += 256) {
        int row = i >> 4, j = i & 15;
        *(u16x8*)&wl[row * 136 + j * 8] = *(const u16x8*)&wsrc[i * 8];
    }
    __syncthreads();
    int bl = t >> 5, c2l = t & 31;
    const u16* w0p = &wl[(2 * c2l) * 136];
    const u16* w1p = &wl[(2 * c2l + 1) * 136];
    for (int bt = bq * 16; bt < bq * 16 + 16; ++bt) {
        int b = bt * 8 + bl;
        const u16x8* up = (const u16x8*)(u + ((size_t)b * 1152 + cg * 64 + 2 * c2l) * 8);
        float u0[8], u1[8];
        unpack8(up[0], u0);
        unpack8(up[1], u1);
        u32 outv[16];
        float sd[16];
#pragma unroll
        for (int d = 0; d < 16; ++d) {
            u16x8 wv0 = *(const u16x8*)&w0p[d * 8];
            u16x8 wv1 = *(const u16x8*)&w1p[d * 8];
            float w0f[8], w1f[8];
            unpack8(wv0, w0f);
            unpack8(wv1, w1f);
            float dA = 0.f, dB = 0.f;
#pragma unroll
            for (int i = 0; i < 8; ++i) {
                dA += w0f[i] * u0[i];
                dB += w1f[i] * u1[i];
            }
            outv[d] = (u32)f2bf(dA) | ((u32)f2bf(dB) << 16);
            sd[d] = dA + dB;
        }
        // butterfly over the 32 c2l lanes -> sum over this block's 64 c's
#pragma unroll
        for (int m = 1; m < 32; m <<= 1)
#pragma unroll
            for (int d = 0; d < 16; ++d) sd[d] += __shfl_xor(sd[d], m, 32);
        if (c2l == 0) {
            float* dst = s0p + ((size_t)cg * 512 + b) * 160 + o * 16;
#pragma unroll
            for (int d = 0; d < 16; ++d) dst[d] = sd[d];
        }
        u32* dstv = uhp + (size_t)b * 92160 + (cg * 32 + c2l) * 160 + o * 16;
#pragma unroll
        for (int k = 0; k < 4; ++k)
            *(u32x4*)&dstv[k * 4] = *(u32x4*)&outv[k * 4];
    }
}

// ---------------- fused dynamic routing: pass0 from s0p + 2 streaming passes ----------------
__global__ __launch_bounds__(256, 2) void k_routing(const u32* __restrict__ uhp,
                                                    const float* __restrict__ s0p,
                                                    float* __restrict__ logits,
                                                    float* __restrict__ masked) {
    int b = blockIdx.x, t = threadIdx.x;
    __shared__ float blog[10][1160];          // 46.4 KB
    __shared__ __align__(16) u32 chunk[32 * 164];  // 21 KB, row stride 164 u32
    __shared__ float cwl[10][66];
    __shared__ float v[160];
    __shared__ float lg[10];
    __shared__ int am;
    for (int i = t; i < 11600; i += 256) ((float*)blog)[i] = 0.f;
    const u32* uh = uhp + (size_t)b * 92160;
    int o16 = t >> 4, d16 = t & 15;
    float s = 0.f;

    // ---- pass 0: uniform coupling 1/10, from precomputed partials ----
    if (t < 160) {
#pragma unroll
        for (int cg = 0; cg < 18; ++cg)
            s += s0p[((size_t)cg * 512 + b) * 160 + t];
        s *= 0.1f;
        float sq = s * s;
        sq += __shfl_xor(sq, 1, 16);
        sq += __shfl_xor(sq, 2, 16);
        sq += __shfl_xor(sq, 4, 16);
        sq += __shfl_xor(sq, 8, 16);
        float scale = (sq / (1.f + sq)) / (sqrtf(sq) + 1e-8f);
        v[t] = s * scale;
    }
    __syncthreads();

    for (int pass = 1; pass < 3; ++pass) {
        float snew = 0.f;
        for (int cg = 0; cg < 18; ++cg) {
            const u32x4* src4 = (const u32x4*)(uh + (size_t)cg * 5120);
#pragma unroll
            for (int k = 0; k < 5; ++k) {
                int idx4 = t + k * 256;
                int c2l = idx4 / 40, j4 = idx4 - c2l * 40;
                ((u32x4*)chunk)[c2l * 41 + j4] = src4[idx4];
            }
            __syncthreads();
#pragma unroll
            for (int jj = 0; jj < 2; ++jj) {
                int idx = t + jj * 256;
                if (idx < 320) {
                    int c2l = idx / 10, o = idx - c2l * 10;
                    const u32* row = &chunk[c2l * 164 + o * 16];
                    const float* vp = &v[o * 16];
                    float d0 = 0.f, d1 = 0.f;
#pragma unroll
                    for (int d = 0; d < 16; ++d) {
                        u32 wv = row[d];
                        float vv = vp[d];
                        d0 += __uint_as_float(wv << 16) * vv;
                        d1 += __uint_as_float(wv & 0xffff0000u) * vv;
                    }
                    int c2 = cg * 32 + c2l;
                    blog[o][2 * c2] += d0;
                    blog[o][2 * c2 + 1] += d1;
                }
            }
            __syncthreads();
            if (t < 64) {
                int c = cg * 64 + t;
                float bb[10], mx = -1e30f;
#pragma unroll
                for (int o = 0; o < 10; ++o) { bb[o] = blog[o][c]; mx = fmaxf(mx, bb[o]); }
                float sum = 0.f;
#pragma unroll
                for (int o = 0; o < 10; ++o) { bb[o] = __expf(bb[o] - mx); sum += bb[o]; }
                float rs = 1.f / sum;
#pragma unroll
                for (int o = 0; o < 10; ++o) cwl[o][t] = bb[o] * rs;
            }
            __syncthreads();
            if (t < 160) {
                const u32* col = &chunk[t];
                const float* cwp = &cwl[o16][0];
#pragma unroll 8
                for (int c2l = 0; c2l < 32; ++c2l) {
                    u32 wv = col[c2l * 164];
                    snew += __uint_as_float(wv << 16) * cwp[2 * c2l] +
                            __uint_as_float(wv & 0xffff0000u) * cwp[2 * c2l + 1];
                }
            }
            __syncthreads();
        }
        if (t < 160) {
            s = snew;
            float sq = s * s;
            sq += __shfl_xor(sq, 1, 16);
            sq += __shfl_xor(sq, 2, 16);
            sq += __shfl_xor(sq, 4, 16);
            sq += __shfl_xor(sq, 8, 16);
            float scale = (sq / (1.f + sq)) / (sqrtf(sq) + 1e-8f);
            v[t] = s * scale;
            if (d16 == 0 && pass == 2) {
                float sn = sqrtf(sq);
                float l = (sq / (1.f + sq)) * (sn / (sn + 1e-8f));
                lg[o16] = l;
                logits[b * 10 + o16] = l;
            }
        }
        __syncthreads();
    }
    if (t == 0) {
        float best = lg[0];
        int bi = 0;
#pragma unroll
        for (int o = 1; o < 10; ++o)
            if (lg[o] > best) { best = lg[o]; bi = o; }
        am = bi;
    }
    __syncthreads();
    if (t < 160) masked[b * 160 + t] = (o16 == am) ? v[t] : 0.f;
}

// ---------------- decoder layer (TB-batch tile) ----------------
template <int TB, int K, int OUTDIM, int ACT>
__global__ __launch_bounds__(256) void k_dec(const float* __restrict__ in,
                                             const float* __restrict__ W,
                                             const float* __restrict__ bias,
                                             float* __restrict__ out) {
    int bt = blockIdx.y * TB;
    int o = blockIdx.x * 256 + threadIdx.x;
    __shared__ float ins[TB * K];
    for (int i = threadIdx.x; i < TB * K; i += 256) ins[i] = in[(size_t)bt * K + i];
    __syncthreads();
    if (o < OUTDIM) {
        float acc[TB];
#pragma unroll
        for (int bb = 0; bb < TB; ++bb) acc[bb] = 0.f;
        const float* wr = W + (size_t)o * K;
#pragma unroll 4
        for (int k = 0; k < K; ++k) {
            float wv = wr[k];
#pragma unroll
            for (int bb = 0; bb < TB; ++bb) acc[bb] += wv * ins[bb * K + k];
        }
        float bv = bias[o];
#pragma unroll
        for (int bb = 0; bb < TB; ++bb) {
            float z = acc[bb] + bv;
            float r = (ACT == 0) ? fmaxf(z, 0.f) : 1.f / (1.f + __expf(-z));
            out[(size_t)(bt + bb) * OUTDIM + o] = r;
        }
    }
}

extern "C" void kernel_launch(void* const* d_in, const int* in_sizes, int n_in,
                              void* d_out, int out_size, void* d_ws, size_t ws_size,
                              hipStream_t stream) {
    const float* x       = (const float*)d_in[0];
    const float* conv1_w = (const float*)d_in[1];
    const float* conv1_b = (const float*)d_in[2];
    const float* prim_w  = (const float*)d_in[3];
    const float* prim_b  = (const float*)d_in[4];
    const float* W_digit = (const float*)d_in[5];
    const float* dec_w1  = (const float*)d_in[6];
    const float* dec_b1  = (const float*)d_in[7];
    const float* dec_w2  = (const float*)d_in[8];
    const float* dec_b2  = (const float*)d_in[9];
    const float* dec_w3  = (const float*)d_in[10];
    const float* dec_b3  = (const float*)d_in[11];

    char* ws = (char*)d_ws;
    u16*   conv1o = (u16*)(ws + OFF_CONV1);
    u16*   cp16   = (u16*)(ws + OFF_CP);
    u32*   uhat   = (u32*)(ws + OFF_UHAT);
    u16*   u      = (u16*)(ws + OFF_U);
    u16*   wrq    = (u16*)(ws + OFF_WR);
    float* s0p    = (float*)(ws + OFF_WR);   // aliases wrq (dead after k_gemm)
    u16*   wb     = (u16*)(ws + OFF_WB);
    u16*   wc2    = (u16*)(ws + OFF_WC2);
    float* maskd  = (float*)(ws + OFF_MASK);
    float* h1     = (float*)(ws + OFF_H1);
    float* h2     = (float*)(ws + OFF_H2);
    float* logits = (float*)d_out;
    float* recon  = (float*)d_out + 5120;

    k_prep<<<dim3(977), dim3(256), 0, stream>>>(conv1_w, wc2, W_digit, wb, prim_w, wrq);
    k_conv1<<<dim3(512), dim3(256), 0, stream>>>(x, wc2, conv1_b, conv1o);
    k_gemm<<<dim3(144, 2, 4), dim3(256), 0, stream>>>(wrq, conv1o, cp16);
    k_squash<<<dim3(2304), dim3(256), 0, stream>>>(cp16, prim_b, u);
    k_uhat<<<dim3(10, 18, 4), dim3(256), 0, stream>>>(u, wb, uhat, s0p);
    k_routing<<<dim3(512), dim3(256), 0, stream>>>(uhat, s0p, logits, maskd);
    k_dec<4, 160, 512, 0><<<dim3(2, 128), dim3(256), 0, stream>>>(maskd, dec_w1, dec_b1, h1);
    k_dec<8, 512, 1024, 0><<<dim3(4, 64), dim3(256), 0, stream>>>(h1, dec_w2, dec_b2, h2);
    k_dec<8, 1024, 784, 1><<<dim3(4, 64), dim3(256), 0, stream>>>(h2, dec_w3, dec_b3, recon);
}